// Round 1
// baseline (7404.085 us; speedup 1.0000x reference)
//
#include <hip/hip_runtime.h>

// Problem constants (from reference)
#define N_NODES 20000
#define BATCH   4
#define DIN     32
#define DOUT    64
#define MSTEPS  7          // M = MAX_STEP*S + 1
#define ROW     128        // DIN*BATCH, channels per node
#define XLEN    (N_NODES*ROW)   // floats per xs buffer = 2,560,000

// x0[n*128 + d*4 + b] = inputs[b*N*D + n*D + d]
__global__ void transpose_in_k(const float* __restrict__ in, float* __restrict__ x0) {
    int tid = blockIdx.x * 256 + threadIdx.x;
    if (tid >= XLEN) return;
    int b = tid & 3;
    int d = (tid >> 2) & 31;
    int n = tid >> 7;
    x0[tid] = in[(b * N_NODES + n) * DIN + d];
}

// y = beta * x  (beta==0 -> pure zero-fill, no read)
__global__ void init_buf_k(float* __restrict__ y, const float* __restrict__ x, float beta) {
    int i = blockIdx.x * 256 + threadIdx.x;
    if (i >= XLEN / 4) return;
    float4 v;
    if (beta == 0.0f) {
        v = make_float4(0.f, 0.f, 0.f, 0.f);
    } else {
        float4 t = ((const float4*)x)[i];
        v = make_float4(beta * t.x, beta * t.y, beta * t.z, beta * t.w);
    }
    ((float4*)y)[i] = v;
}

// y[dst[e]] += alpha * vals[e] * x[src[e]]   (32 lanes per edge, float4 per lane)
__global__ void spmm_atomic_k(const float* __restrict__ vals, const int* __restrict__ src,
                              const int* __restrict__ dst, const float* __restrict__ x,
                              float* __restrict__ y, float alpha, int E) {
    int tid = blockIdx.x * 256 + threadIdx.x;
    int e = tid >> 5;
    if (e >= E) return;
    int q = tid & 31;
    float v = alpha * vals[e];
    int s = src[e];
    int d = dst[e];
    float4 xv = ((const float4*)(x + (long)s * ROW))[q];
    float* yp = y + (long)d * ROW + q * 4;
    atomicAdd(yp + 0, v * xv.x);
    atomicAdd(yp + 1, v * xv.y);
    atomicAdd(yp + 2, v * xv.z);
    atomicAdd(yp + 3, v * xv.w);
}

// out[b,n,o] (+)= sum_d xs[n*128 + d*4 + b] * W[o*224 + d*7 + m]  (+ bias on first)
// one wave per (b,n); lanes = o (64) -> coalesced out access
__global__ void out_pass_k(const float* __restrict__ xs, const float* __restrict__ W,
                           const float* __restrict__ bias, float* __restrict__ out,
                           int m, int first) {
    __shared__ float Wl[DIN][DOUT];   // 8 KB
    int t = threadIdx.x;
    for (int i = t; i < DIN * DOUT; i += 256) {
        int d = i >> 6, o = i & 63;
        Wl[d][o] = W[o * (DIN * MSTEPS) + d * MSTEPS + m];
    }
    __syncthreads();
    int wave = blockIdx.x * 4 + (t >> 6);   // 80,000 waves total, exact
    int o = t & 63;
    int b = wave / N_NODES;
    int n = wave - b * N_NODES;
    const float* xrow = xs + n * ROW + b;
    long oidx = ((long)b * N_NODES + n) * DOUT + o;
    float acc = first ? bias[o] : out[oidx];
#pragma unroll
    for (int d = 0; d < DIN; ++d)
        acc = fmaf(xrow[d * 4], Wl[d][o], acc);
    out[oidx] = acc;
}

extern "C" void kernel_launch(void* const* d_in, const int* in_sizes, int n_in,
                              void* d_out, int out_size, void* d_ws, size_t ws_size,
                              hipStream_t stream) {
    const float* inputs    = (const float*)d_in[0];
    const float* edge_vals = (const float*)d_in[1];
    const float* W         = (const float*)d_in[2];
    const float* bias      = (const float*)d_in[3];
    const int*   edge_src  = (const int*)d_in[4];
    const int*   edge_dst  = (const int*)d_in[5];
    float* out = (float*)d_out;
    const int E = in_sizes[1] / 2;   // edges per support

    float* b0 = (float*)d_ws;
    float* b1 = b0 + XLEN;
    float* b2 = b1 + XLEN;

    const int tgrid = (XLEN + 255) / 256;
    const int igrid = (XLEN / 4 + 255) / 256;
    const int sgrid = (E * 32 + 255) / 256;
    const int ogrid = (BATCH * N_NODES) / 4;   // 4 waves/block

    const float* v0 = edge_vals;     const int* s0 = edge_src;     const int* d0 = edge_dst;
    const float* v1 = edge_vals + E; const int* s1 = edge_src + E; const int* d1 = edge_dst + E;

    // xs0 = X0
    transpose_in_k<<<tgrid, 256, 0, stream>>>(inputs, b0);
    out_pass_k<<<ogrid, 256, 0, stream>>>(b0, W, bias, out, 0, 1);

    // xs1 = A0 * xs0            -> b1
    init_buf_k<<<igrid, 256, 0, stream>>>(b1, nullptr, 0.0f);
    spmm_atomic_k<<<sgrid, 256, 0, stream>>>(v0, s0, d0, b0, b1, 1.0f, E);
    out_pass_k<<<ogrid, 256, 0, stream>>>(b1, W, bias, out, 1, 0);

    // xs2 = 2*A0*xs1 - xs0      -> b2
    init_buf_k<<<igrid, 256, 0, stream>>>(b2, b0, -1.0f);
    spmm_atomic_k<<<sgrid, 256, 0, stream>>>(v0, s0, d0, b1, b2, 2.0f, E);
    out_pass_k<<<ogrid, 256, 0, stream>>>(b2, W, bias, out, 2, 0);

    // xs3 = 2*A0*xs2 - xs1      -> b0
    init_buf_k<<<igrid, 256, 0, stream>>>(b0, b1, -1.0f);
    spmm_atomic_k<<<sgrid, 256, 0, stream>>>(v0, s0, d0, b2, b0, 2.0f, E);
    out_pass_k<<<ogrid, 256, 0, stream>>>(b0, W, bias, out, 3, 0);

    // xs4 = A1 * xs2            -> b1   (xs1 dead)
    init_buf_k<<<igrid, 256, 0, stream>>>(b1, nullptr, 0.0f);
    spmm_atomic_k<<<sgrid, 256, 0, stream>>>(v1, s1, d1, b2, b1, 1.0f, E);
    out_pass_k<<<ogrid, 256, 0, stream>>>(b1, W, bias, out, 4, 0);

    // xs5 = 2*A1*xs4 - xs2      -> b0   (xs3 dead)
    init_buf_k<<<igrid, 256, 0, stream>>>(b0, b2, -1.0f);
    spmm_atomic_k<<<sgrid, 256, 0, stream>>>(v1, s1, d1, b1, b0, 2.0f, E);
    out_pass_k<<<ogrid, 256, 0, stream>>>(b0, W, bias, out, 5, 0);

    // xs6 = 2*A1*xs5 - xs4      -> b2
    init_buf_k<<<igrid, 256, 0, stream>>>(b2, b1, -1.0f);
    spmm_atomic_k<<<sgrid, 256, 0, stream>>>(v1, s1, d1, b0, b2, 2.0f, E);
    out_pass_k<<<ogrid, 256, 0, stream>>>(b2, W, bias, out, 6, 0);
}

// Round 2
// 1403.336 us; speedup vs baseline: 5.2761x; 5.2761x over previous
//
#include <hip/hip_runtime.h>

// Problem constants (from reference)
#define N_NODES 20000
#define BATCH   4
#define DIN     32
#define DOUT    64
#define MSTEPS  7          // M = MAX_STEP*S + 1
#define ROW     128        // DIN*BATCH, channels per node
#define XLEN    (N_NODES*ROW)   // floats per xs buffer = 2,560,000

// x0[n*128 + d*4 + b] = inputs[b*N*D + n*D + d]
__global__ void transpose_in_k(const float* __restrict__ in, float* __restrict__ x0) {
    int tid = blockIdx.x * 256 + threadIdx.x;
    if (tid >= XLEN) return;
    int b = tid & 3;
    int d = (tid >> 2) & 31;
    int n = tid >> 7;
    x0[tid] = in[(b * N_NODES + n) * DIN + d];
}

// ---- CSR build (per call; same work every call) ----

__global__ void zero_cnt_k(int* __restrict__ cnt) {
    int i = blockIdx.x * 256 + threadIdx.x;
    if (i < 2 * N_NODES) cnt[i] = 0;
}

// histogram of dst for both supports at once; dst laid out [S, E]
__global__ void hist_k(const int* __restrict__ dst, int* __restrict__ cnt, int E) {
    int i = blockIdx.x * 256 + threadIdx.x;
    if (i >= 2 * E) return;
    int s = (i >= E) ? 1 : 0;
    atomicAdd(&cnt[s * N_NODES + dst[i]], 1);
}

// one block per support: inclusive scan of cnt -> row_ptr (excl, N+1) and cursor (excl)
__global__ void scan_k(const int* __restrict__ cnt, int* __restrict__ row_ptr,
                       int* __restrict__ cursor) {
    int s = blockIdx.x;
    const int* c = cnt + s * N_NODES;
    int* rp  = row_ptr + s * (N_NODES + 1);
    int* cur = cursor + s * N_NODES;
    __shared__ int sh[1024];
    __shared__ int carry_sh;
    int t = threadIdx.x;
    if (t == 0) { rp[0] = 0; carry_sh = 0; }
    __syncthreads();
    for (int base = 0; base < N_NODES; base += 1024) {
        int i = base + t;
        int v = (i < N_NODES) ? c[i] : 0;
        sh[t] = v;
        __syncthreads();
        for (int off = 1; off < 1024; off <<= 1) {
            int add = (t >= off) ? sh[t - off] : 0;
            __syncthreads();
            sh[t] += add;
            __syncthreads();
        }
        int carry = carry_sh;
        int incl = sh[t] + carry;
        if (i < N_NODES) {
            rp[i + 1] = incl;
            cur[i] = incl - v;
        }
        __syncthreads();
        if (t == 1023) carry_sh = incl;
        __syncthreads();
    }
}

__global__ void scatter_k(const int* __restrict__ src, const int* __restrict__ dst,
                          const float* __restrict__ vals, int* __restrict__ cursor,
                          int* __restrict__ csr_src, float* __restrict__ csr_val, int E) {
    int i = blockIdx.x * 256 + threadIdx.x;
    if (i >= 2 * E) return;
    int s = (i >= E) ? 1 : 0;
    int d = dst[i];
    int pos = atomicAdd(&cursor[s * N_NODES + d], 1);
    size_t o = (size_t)s * E + pos;
    csr_src[o] = src[i];
    csr_val[o] = vals[i];
}

// ---- SpMM, gather side: y[n] = alpha * sum_e val[e]*x[src[e]]  (- xprev[n] if given) ----
// one wave per node, lane = float2 channel pair (64*2 = 128 channels)
__global__ void spmm_row_k(const int* __restrict__ row_ptr, const int* __restrict__ csr_src,
                           const float* __restrict__ csr_val, const float* __restrict__ x,
                           const float* __restrict__ xprev, float* __restrict__ y,
                           float alpha) {
    int wave = blockIdx.x * 4 + (threadIdx.x >> 6);
    if (wave >= N_NODES) return;
    int lane = threadIdx.x & 63;
    int start = row_ptr[wave], end = row_ptr[wave + 1];
    float2 acc0 = make_float2(0.f, 0.f), acc1 = make_float2(0.f, 0.f);
    int e = start;
    for (; e + 2 <= end; e += 2) {
        float va = csr_val[e],     vb = csr_val[e + 1];
        int   sa = csr_src[e],     sb = csr_src[e + 1];
        float2 xa = ((const float2*)(x + (size_t)sa * ROW))[lane];
        float2 xb = ((const float2*)(x + (size_t)sb * ROW))[lane];
        acc0.x = fmaf(va, xa.x, acc0.x);
        acc0.y = fmaf(va, xa.y, acc0.y);
        acc1.x = fmaf(vb, xb.x, acc1.x);
        acc1.y = fmaf(vb, xb.y, acc1.y);
    }
    if (e < end) {
        float va = csr_val[e];
        int   sa = csr_src[e];
        float2 xa = ((const float2*)(x + (size_t)sa * ROW))[lane];
        acc0.x = fmaf(va, xa.x, acc0.x);
        acc0.y = fmaf(va, xa.y, acc0.y);
    }
    float2 r;
    r.x = alpha * (acc0.x + acc1.x);
    r.y = alpha * (acc0.y + acc1.y);
    if (xprev) {
        float2 p = ((const float2*)(xprev + (size_t)wave * ROW))[lane];
        r.x -= p.x;
        r.y -= p.y;
    }
    ((float2*)(y + (size_t)wave * ROW))[lane] = r;
}

// out[b,n,o] (+)= sum_d xs[n*128 + d*4 + b] * W[o*224 + d*7 + m]  (+ bias on first)
__global__ void out_pass_k(const float* __restrict__ xs, const float* __restrict__ W,
                           const float* __restrict__ bias, float* __restrict__ out,
                           int m, int first) {
    __shared__ float Wl[DIN][DOUT];   // 8 KB
    int t = threadIdx.x;
    for (int i = t; i < DIN * DOUT; i += 256) {
        int d = i >> 6, o = i & 63;
        Wl[d][o] = W[o * (DIN * MSTEPS) + d * MSTEPS + m];
    }
    __syncthreads();
    int wave = blockIdx.x * 4 + (t >> 6);   // 80,000 waves total, exact
    int o = t & 63;
    int b = wave / N_NODES;
    int n = wave - b * N_NODES;
    const float* xrow = xs + n * ROW + b;
    long oidx = ((long)b * N_NODES + n) * DOUT + o;
    float acc = first ? bias[o] : out[oidx];
#pragma unroll
    for (int d = 0; d < DIN; ++d)
        acc = fmaf(xrow[d * 4], Wl[d][o], acc);
    out[oidx] = acc;
}

extern "C" void kernel_launch(void* const* d_in, const int* in_sizes, int n_in,
                              void* d_out, int out_size, void* d_ws, size_t ws_size,
                              hipStream_t stream) {
    const float* inputs    = (const float*)d_in[0];
    const float* edge_vals = (const float*)d_in[1];
    const float* W         = (const float*)d_in[2];
    const float* bias      = (const float*)d_in[3];
    const int*   edge_src  = (const int*)d_in[4];
    const int*   edge_dst  = (const int*)d_in[5];
    float* out = (float*)d_out;
    const int E = in_sizes[1] / 2;   // edges per support

    float* b0 = (float*)d_ws;
    float* b1 = b0 + XLEN;
    float* b2 = b1 + XLEN;
    int* cnt     = (int*)(b2 + XLEN);          // 2*N
    int* row_ptr = cnt + 2 * N_NODES;          // 2*(N+1)
    int* cursor  = row_ptr + 2 * (N_NODES + 1);// 2*N
    int* csr_src = cursor + 2 * N_NODES;       // 2*E
    float* csr_val = (float*)(csr_src + 2 * E);// 2*E

    const int tgrid = (XLEN + 255) / 256;
    const int egrid = (2 * E + 255) / 256;
    const int rgrid = N_NODES / 4;             // 4 waves/block, exact
    const int ogrid = (BATCH * N_NODES) / 4;

    // ---- CSR build for both supports ----
    zero_cnt_k<<<(2 * N_NODES + 255) / 256, 256, 0, stream>>>(cnt);
    hist_k<<<egrid, 256, 0, stream>>>(edge_dst, cnt, E);
    scan_k<<<2, 1024, 0, stream>>>(cnt, row_ptr, cursor);
    scatter_k<<<egrid, 256, 0, stream>>>(edge_src, edge_dst, edge_vals, cursor,
                                         csr_src, csr_val, E);

    const int* rp0 = row_ptr;                 const int* rp1 = row_ptr + (N_NODES + 1);
    const int* cs0 = csr_src;                 const int* cs1 = csr_src + E;
    const float* cv0 = csr_val;               const float* cv1 = csr_val + E;

    // xs0 = X0
    transpose_in_k<<<tgrid, 256, 0, stream>>>(inputs, b0);
    out_pass_k<<<ogrid, 256, 0, stream>>>(b0, W, bias, out, 0, 1);

    // xs1 = A0 * xs0            -> b1
    spmm_row_k<<<rgrid, 256, 0, stream>>>(rp0, cs0, cv0, b0, nullptr, b1, 1.0f);
    out_pass_k<<<ogrid, 256, 0, stream>>>(b1, W, bias, out, 1, 0);

    // xs2 = 2*A0*xs1 - xs0      -> b2
    spmm_row_k<<<rgrid, 256, 0, stream>>>(rp0, cs0, cv0, b1, b0, b2, 2.0f);
    out_pass_k<<<ogrid, 256, 0, stream>>>(b2, W, bias, out, 2, 0);

    // xs3 = 2*A0*xs2 - xs1      -> b0
    spmm_row_k<<<rgrid, 256, 0, stream>>>(rp0, cs0, cv0, b2, b1, b0, 2.0f);
    out_pass_k<<<ogrid, 256, 0, stream>>>(b0, W, bias, out, 3, 0);

    // xs4 = A1 * xs2            -> b1
    spmm_row_k<<<rgrid, 256, 0, stream>>>(rp1, cs1, cv1, b2, nullptr, b1, 1.0f);
    out_pass_k<<<ogrid, 256, 0, stream>>>(b1, W, bias, out, 4, 0);

    // xs5 = 2*A1*xs4 - xs2      -> b0
    spmm_row_k<<<rgrid, 256, 0, stream>>>(rp1, cs1, cv1, b1, b2, b0, 2.0f);
    out_pass_k<<<ogrid, 256, 0, stream>>>(b0, W, bias, out, 5, 0);

    // xs6 = 2*A1*xs5 - xs4      -> b2
    spmm_row_k<<<rgrid, 256, 0, stream>>>(rp1, cs1, cv1, b0, b1, b2, 2.0f);
    out_pass_k<<<ogrid, 256, 0, stream>>>(b2, W, bias, out, 6, 0);
}

// Round 3
// 655.177 us; speedup vs baseline: 11.3009x; 2.1419x over previous
//
#include <hip/hip_runtime.h>

// Problem constants (from reference)
#define N_NODES 20000
#define BATCH   4
#define DIN     32
#define DOUT    64
#define MSTEPS  7            // M = MAX_STEP*S + 1
#define ROW     128          // DIN*BATCH, channels per node
#define NROW    896          // ROW*MSTEPS floats per node (all m packed)
#define EP_NPB  40           // epilogue: nodes per block (20000/500)
#define EP_NPI  4            // epilogue: nodes per iteration (= waves/block)

// xs_all[n*896 + 0*128 + d*4 + b] = inputs[b*N*D + n*D + d]   (slice m=0)
__global__ void transpose_in_k(const float* __restrict__ in, float* __restrict__ xs_all) {
    int tid = blockIdx.x * 256 + threadIdx.x;
    if (tid >= N_NODES * ROW) return;
    int b = tid & 3;
    int d = (tid >> 2) & 31;
    int n = tid >> 7;
    xs_all[(size_t)n * NROW + d * 4 + b] = in[(b * N_NODES + n) * DIN + d];
}

// ---- CSR build (per call; same work every call) ----

__global__ void zero_cnt_k(int* __restrict__ cnt) {
    int i = blockIdx.x * 256 + threadIdx.x;
    if (i < 2 * N_NODES) cnt[i] = 0;
}

__global__ void hist_k(const int* __restrict__ dst, int* __restrict__ cnt, int E) {
    int i = blockIdx.x * 256 + threadIdx.x;
    if (i >= 2 * E) return;
    int s = (i >= E) ? 1 : 0;
    atomicAdd(&cnt[s * N_NODES + dst[i]], 1);
}

// one block per support: scan of cnt -> row_ptr (N+1) and cursor (excl offsets)
__global__ void scan_k(const int* __restrict__ cnt, int* __restrict__ row_ptr,
                       int* __restrict__ cursor) {
    int s = blockIdx.x;
    const int* c = cnt + s * N_NODES;
    int* rp  = row_ptr + s * (N_NODES + 1);
    int* cur = cursor + s * N_NODES;
    __shared__ int sh[1024];
    __shared__ int carry_sh;
    int t = threadIdx.x;
    if (t == 0) { rp[0] = 0; carry_sh = 0; }
    __syncthreads();
    for (int base = 0; base < N_NODES; base += 1024) {
        int i = base + t;
        int v = (i < N_NODES) ? c[i] : 0;
        sh[t] = v;
        __syncthreads();
        for (int off = 1; off < 1024; off <<= 1) {
            int add = (t >= off) ? sh[t - off] : 0;
            __syncthreads();
            sh[t] += add;
            __syncthreads();
        }
        int carry = carry_sh;
        int incl = sh[t] + carry;
        if (i < N_NODES) {
            rp[i + 1] = incl;
            cur[i] = incl - v;
        }
        __syncthreads();
        if (t == 1023) carry_sh = incl;
        __syncthreads();
    }
}

__global__ void scatter_k(const int* __restrict__ src, const int* __restrict__ dst,
                          const float* __restrict__ vals, int* __restrict__ cursor,
                          int* __restrict__ csr_src, float* __restrict__ csr_val, int E) {
    int i = blockIdx.x * 256 + threadIdx.x;
    if (i >= 2 * E) return;
    int s = (i >= E) ? 1 : 0;
    int d = dst[i];
    int pos = atomicAdd(&cursor[s * N_NODES + d], 1);
    size_t o = (size_t)s * E + pos;
    csr_src[o] = src[i];
    csr_val[o] = vals[i];
}

// ---- SpMM gather: y_row[n] = alpha * sum_e val*x_row[src]  (- prev_row[n] if prev)
// x/y/prev point at xs_all + m*128; node rows at stride NROW.
__global__ void spmm_row_k(const int* __restrict__ row_ptr, const int* __restrict__ csr_src,
                           const float* __restrict__ csr_val, const float* __restrict__ x,
                           const float* __restrict__ xprev, float* __restrict__ y,
                           float alpha) {
    int node = blockIdx.x * 4 + (threadIdx.x >> 6);
    if (node >= N_NODES) return;
    int lane = threadIdx.x & 63;
    int start = row_ptr[node], end = row_ptr[node + 1];
    float2 acc0 = make_float2(0.f, 0.f), acc1 = make_float2(0.f, 0.f);
    int e = start;
    for (; e + 2 <= end; e += 2) {
        float va = csr_val[e],     vb = csr_val[e + 1];
        int   sa = csr_src[e],     sb = csr_src[e + 1];
        float2 xa = ((const float2*)(x + (size_t)sa * NROW))[lane];
        float2 xb = ((const float2*)(x + (size_t)sb * NROW))[lane];
        acc0.x = fmaf(va, xa.x, acc0.x);
        acc0.y = fmaf(va, xa.y, acc0.y);
        acc1.x = fmaf(vb, xb.x, acc1.x);
        acc1.y = fmaf(vb, xb.y, acc1.y);
    }
    if (e < end) {
        float va = csr_val[e];
        int   sa = csr_src[e];
        float2 xa = ((const float2*)(x + (size_t)sa * NROW))[lane];
        acc0.x = fmaf(va, xa.x, acc0.x);
        acc0.y = fmaf(va, xa.y, acc0.y);
    }
    float2 r;
    r.x = alpha * (acc0.x + acc1.x);
    r.y = alpha * (acc0.y + acc1.y);
    if (xprev) {
        float2 p = ((const float2*)(xprev + (size_t)node * NROW))[lane];
        r.x -= p.x;
        r.y -= p.y;
    }
    ((float2*)(y + (size_t)node * NROW))[lane] = r;
}

// ---- Fused epilogue: out[b,n,o] = bias[o] + sum_{m,d} xs_all[n][m][d*4+b] * W[o][d*7+m]
// wave = node slot (4 nodes/iter), lane = o; thread accumulates all 4 batches.
__global__ void __launch_bounds__(256) epilogue_k(const float* __restrict__ xs_all,
                                                  const float* __restrict__ W,
                                                  const float* __restrict__ bias,
                                                  float* __restrict__ out) {
    __shared__ float Wl[224 * 64];        // 57344 B, Wl[k*64+o] = W[o*224+k]
    __shared__ float xsh[EP_NPI * NROW];  // 14336 B
    int tid = threadIdx.x;
    int o = tid & 63;
    int w = tid >> 6;
    // stage W transposed; global reads are float4 (uncoalesced across lanes but
    // W is 57 KB and L2-hot); LDS writes conflict-free (lane stride 1 in o)
    for (int f4 = tid; f4 < 224 * 64 / 4; f4 += 256) {
        int o2 = f4 & 63;
        int k4 = f4 >> 6;     // 0..55
        float4 wv = ((const float4*)(W + o2 * 224))[k4];
        int base = (k4 * 4) * 64 + o2;
        Wl[base      ] = wv.x;
        Wl[base +  64] = wv.y;
        Wl[base + 128] = wv.z;
        Wl[base + 192] = wv.w;
    }
    float bo = bias[o];
    int node0 = blockIdx.x * EP_NPB;
    for (int it = 0; it < EP_NPB / EP_NPI; ++it) {
        int nbase = node0 + it * EP_NPI;
        __syncthreads();   // xsh safe to overwrite (also orders W staging once)
        const float4* gsrc = (const float4*)(xs_all + (size_t)nbase * NROW);
        float4* ldst = (float4*)xsh;
        for (int f4 = tid; f4 < EP_NPI * NROW / 4; f4 += 256)
            ldst[f4] = gsrc[f4];
        __syncthreads();
        float acc0 = bo, acc1 = bo, acc2 = bo, acc3 = bo;
        const float* xr = xsh + w * NROW;
        for (int m = 0; m < MSTEPS; ++m) {
#pragma unroll
            for (int d = 0; d < DIN; ++d) {
                float wv = Wl[(d * MSTEPS + m) * 64 + o];           // stride-1, 2/bank
                float4 xv = *(const float4*)(xr + m * 128 + d * 4); // wave-uniform bcast
                acc0 = fmaf(xv.x, wv, acc0);
                acc1 = fmaf(xv.y, wv, acc1);
                acc2 = fmaf(xv.z, wv, acc2);
                acc3 = fmaf(xv.w, wv, acc3);
            }
        }
        int n = nbase + w;
        out[((size_t)0 * N_NODES + n) * DOUT + o] = acc0;
        out[((size_t)1 * N_NODES + n) * DOUT + o] = acc1;
        out[((size_t)2 * N_NODES + n) * DOUT + o] = acc2;
        out[((size_t)3 * N_NODES + n) * DOUT + o] = acc3;
    }
}

extern "C" void kernel_launch(void* const* d_in, const int* in_sizes, int n_in,
                              void* d_out, int out_size, void* d_ws, size_t ws_size,
                              hipStream_t stream) {
    const float* inputs    = (const float*)d_in[0];
    const float* edge_vals = (const float*)d_in[1];
    const float* W         = (const float*)d_in[2];
    const float* bias      = (const float*)d_in[3];
    const int*   edge_src  = (const int*)d_in[4];
    const int*   edge_dst  = (const int*)d_in[5];
    float* out = (float*)d_out;
    const int E = in_sizes[1] / 2;   // edges per support

    float* xs_all = (float*)d_ws;                       // N*896 floats = 71.68 MB
    int* cnt      = (int*)(xs_all + (size_t)N_NODES * NROW);  // 2*N
    int* row_ptr  = cnt + 2 * N_NODES;                  // 2*(N+1)
    int* cursor   = row_ptr + 2 * (N_NODES + 1);        // 2*N
    int* csr_src  = cursor + 2 * N_NODES;               // 2*E
    float* csr_val = (float*)(csr_src + 2 * E);         // 2*E

    const int tgrid = (N_NODES * ROW + 255) / 256;
    const int egrid = (2 * E + 255) / 256;
    const int rgrid = N_NODES / 4;   // 4 nodes(waves)/block, exact
    const int epgrid = N_NODES / EP_NPB;

    // ---- CSR build for both supports ----
    zero_cnt_k<<<(2 * N_NODES + 255) / 256, 256, 0, stream>>>(cnt);
    hist_k<<<egrid, 256, 0, stream>>>(edge_dst, cnt, E);
    scan_k<<<2, 1024, 0, stream>>>(cnt, row_ptr, cursor);
    scatter_k<<<egrid, 256, 0, stream>>>(edge_src, edge_dst, edge_vals, cursor,
                                         csr_src, csr_val, E);

    const int* rp0 = row_ptr;   const int* rp1 = row_ptr + (N_NODES + 1);
    const int* cs0 = csr_src;   const int* cs1 = csr_src + E;
    const float* cv0 = csr_val; const float* cv1 = csr_val + E;

    // slice helper: xs_m base = xs_all + m*128 (node stride NROW)
    float* X0 = xs_all + 0 * ROW;
    float* X1 = xs_all + 1 * ROW;
    float* X2 = xs_all + 2 * ROW;
    float* X3 = xs_all + 3 * ROW;
    float* X4 = xs_all + 4 * ROW;
    float* X5 = xs_all + 5 * ROW;
    float* X6 = xs_all + 6 * ROW;

    // xs0 = X0
    transpose_in_k<<<tgrid, 256, 0, stream>>>(inputs, xs_all);

    // support 0: xs1 = A0 x0 ; xs2 = 2 A0 xs1 - xs0 ; xs3 = 2 A0 xs2 - xs1
    spmm_row_k<<<rgrid, 256, 0, stream>>>(rp0, cs0, cv0, X0, nullptr, X1, 1.0f);
    spmm_row_k<<<rgrid, 256, 0, stream>>>(rp0, cs0, cv0, X1, X0,      X2, 2.0f);
    spmm_row_k<<<rgrid, 256, 0, stream>>>(rp0, cs0, cv0, X2, X1,      X3, 2.0f);
    // support 1 (aliasing quirk: starts from xs2): xs4 = A1 xs2 ; xs5 = 2 A1 xs4 - xs2 ;
    // xs6 = 2 A1 xs5 - xs4
    spmm_row_k<<<rgrid, 256, 0, stream>>>(rp1, cs1, cv1, X2, nullptr, X4, 1.0f);
    spmm_row_k<<<rgrid, 256, 0, stream>>>(rp1, cs1, cv1, X4, X2,      X5, 2.0f);
    spmm_row_k<<<rgrid, 256, 0, stream>>>(rp1, cs1, cv1, X5, X4,      X6, 2.0f);

    // fused epilogue
    epilogue_k<<<epgrid, 256, 0, stream>>>(xs_all, W, bias, out);
}

// Round 4
// 532.421 us; speedup vs baseline: 13.9064x; 1.2306x over previous
//
#include <hip/hip_runtime.h>

// Problem constants (from reference)
#define N_NODES 20000
#define BATCH   4
#define DIN     32
#define DOUT    64
#define MSTEPS  7            // M = MAX_STEP*S + 1
#define ROW     128          // DIN*BATCH, channels per node
#define NROW    896          // ROW*MSTEPS elements per node (all m packed), bf16
#define PLN     656          // LDS plane stride (shorts): 16 rows * 40 + 16 pad

typedef short  short8 __attribute__((ext_vector_type(8)));
typedef float  f32x4  __attribute__((ext_vector_type(4)));

__device__ __forceinline__ unsigned short f2bf(float f) {
    unsigned u = __float_as_uint(f);
    unsigned r = u + 0x7fff + ((u >> 16) & 1);   // RNE to bf16
    return (unsigned short)(r >> 16);
}
__device__ __forceinline__ float bf_lo(unsigned p) { return __uint_as_float(p << 16); }
__device__ __forceinline__ float bf_hi(unsigned p) { return __uint_as_float(p & 0xffff0000u); }

// xs[n*896 + d*4 + b] = bf16(inputs[b*N*D + n*D + d])   (slice m=0)
__global__ void transpose_in_k(const float* __restrict__ in, unsigned short* __restrict__ xs) {
    int tid = blockIdx.x * 256 + threadIdx.x;
    if (tid >= N_NODES * ROW) return;
    int b = tid & 3;
    int d = (tid >> 2) & 31;
    int n = tid >> 7;
    xs[(size_t)n * NROW + d * 4 + b] = f2bf(in[(b * N_NODES + n) * DIN + d]);
}

// ---- CSR build (per call; same work every call) ----

__global__ void zero_cnt_k(int* __restrict__ cnt) {
    int i = blockIdx.x * 256 + threadIdx.x;
    if (i < 2 * N_NODES) cnt[i] = 0;
}

__global__ void hist_k(const int* __restrict__ dst, int* __restrict__ cnt, int E) {
    int i = blockIdx.x * 256 + threadIdx.x;
    if (i >= 2 * E) return;
    int s = (i >= E) ? 1 : 0;
    atomicAdd(&cnt[s * N_NODES + dst[i]], 1);
}

__global__ void scan_k(const int* __restrict__ cnt, int* __restrict__ row_ptr,
                       int* __restrict__ cursor) {
    int s = blockIdx.x;
    const int* c = cnt + s * N_NODES;
    int* rp  = row_ptr + s * (N_NODES + 1);
    int* cur = cursor + s * N_NODES;
    __shared__ int sh[1024];
    __shared__ int carry_sh;
    int t = threadIdx.x;
    if (t == 0) { rp[0] = 0; carry_sh = 0; }
    __syncthreads();
    for (int base = 0; base < N_NODES; base += 1024) {
        int i = base + t;
        int v = (i < N_NODES) ? c[i] : 0;
        sh[t] = v;
        __syncthreads();
        for (int off = 1; off < 1024; off <<= 1) {
            int add = (t >= off) ? sh[t - off] : 0;
            __syncthreads();
            sh[t] += add;
            __syncthreads();
        }
        int carry = carry_sh;
        int incl = sh[t] + carry;
        if (i < N_NODES) {
            rp[i + 1] = incl;
            cur[i] = incl - v;
        }
        __syncthreads();
        if (t == 1023) carry_sh = incl;
        __syncthreads();
    }
}

__global__ void scatter_k(const int* __restrict__ src, const int* __restrict__ dst,
                          const float* __restrict__ vals, int* __restrict__ cursor,
                          int* __restrict__ csr_src, float* __restrict__ csr_val, int E) {
    int i = blockIdx.x * 256 + threadIdx.x;
    if (i >= 2 * E) return;
    int s = (i >= E) ? 1 : 0;
    int d = dst[i];
    int pos = atomicAdd(&cursor[s * N_NODES + d], 1);
    size_t o = (size_t)s * E + pos;
    csr_src[o] = src[i];
    csr_val[o] = vals[i];
}

// ---- SpMM gather, bf16 states: y_row[n] = bf16( alpha*sum val*x_row[src] - prev )
// x/y/prev point at xs + m*128 (element slices); node stride NROW elements.
// lane reads 2 channels packed in one uint (4 B) -> 256 B contiguous per edge.
__global__ void spmm_row_k(const int* __restrict__ row_ptr, const int* __restrict__ csr_src,
                           const float* __restrict__ csr_val,
                           const unsigned short* __restrict__ x,
                           const unsigned short* __restrict__ xprev,
                           unsigned short* __restrict__ y, float alpha) {
    int node = blockIdx.x * 4 + (threadIdx.x >> 6);
    if (node >= N_NODES) return;
    int lane = threadIdx.x & 63;
    int start = row_ptr[node], end = row_ptr[node + 1];
    float a0 = 0.f, a1 = 0.f, b0 = 0.f, b1 = 0.f;
    int e = start;
    for (; e + 2 <= end; e += 2) {
        float va = csr_val[e],  vb = csr_val[e + 1];
        int   sa = csr_src[e],  sb = csr_src[e + 1];
        unsigned pa = ((const unsigned*)(x + (size_t)sa * NROW))[lane];
        unsigned pb = ((const unsigned*)(x + (size_t)sb * NROW))[lane];
        a0 = fmaf(va, bf_lo(pa), a0);
        a1 = fmaf(va, bf_hi(pa), a1);
        b0 = fmaf(vb, bf_lo(pb), b0);
        b1 = fmaf(vb, bf_hi(pb), b1);
    }
    if (e < end) {
        float va = csr_val[e];
        int   sa = csr_src[e];
        unsigned pa = ((const unsigned*)(x + (size_t)sa * NROW))[lane];
        a0 = fmaf(va, bf_lo(pa), a0);
        a1 = fmaf(va, bf_hi(pa), a1);
    }
    float r0 = alpha * (a0 + b0);
    float r1 = alpha * (a1 + b1);
    if (xprev) {
        unsigned pp = ((const unsigned*)(xprev + (size_t)node * NROW))[lane];
        r0 -= bf_lo(pp);
        r1 -= bf_hi(pp);
    }
    unsigned po = (unsigned)f2bf(r0) | ((unsigned)f2bf(r1) << 16);
    ((unsigned*)(y + (size_t)node * NROW))[lane] = po;
}

// ---- MFMA epilogue: out[b,n,o] = bias[o] + sum_{k} A[(b,n),k] * W[o,k]
// GEMM k reordered as k = m*32 + d (same permutation on A and W).
// Block: 16 nodes; wave ot handles o = ot*16..+15 for all 4 batches.
// A staged in LDS as [b][m][row=0..15][d=0..31] bf16, row stride 40, plane stride 656.
__global__ void __launch_bounds__(256) epilogue_mfma_k(const unsigned short* __restrict__ xs,
                                                       const float* __restrict__ W,
                                                       const float* __restrict__ bias,
                                                       float* __restrict__ out) {
    __shared__ unsigned short Alds[28 * PLN];   // 36736 B
    int tid = threadIdx.x;
    int lane = tid & 63, ot = tid >> 6;
    int col = lane & 15, quad = lane >> 4;
    int o = ot * 16 + col;

    // B fragments in registers: B[k'=quad*8+j][col], k' within chunk m.
    // global k = m*32 + k'  ->  W[o*224 + k'*7 + m]
    short8 bfrag[MSTEPS];
#pragma unroll
    for (int m = 0; m < MSTEPS; ++m) {
        short8 bf;
#pragma unroll
        for (int j = 0; j < 8; ++j)
            bf[j] = (short)f2bf(W[o * 224 + (quad * 8 + j) * 7 + m]);
        bfrag[m] = bf;
    }
    float bo = bias[o];

    // Stage 16 node-rows (16*896 bf16 = 28672 B) into A-fragment layout.
    int n0 = blockIdx.x * 16;
    const uint4* src = (const uint4*)(xs + (size_t)n0 * NROW);   // 1792 uint4
#pragma unroll
    for (int it = 0; it < 7; ++it) {
        int idx = tid + it * 256;
        uint4 q = src[idx];
        int r    = idx / 112;            // node row 0..15
        int off8 = idx - r * 112;        // element-octet within row
        int m    = off8 >> 4;
        int d0   = (off8 & 15) * 2;
        unsigned vals[4] = {q.x, q.y, q.z, q.w};
#pragma unroll
        for (int h = 0; h < 4; ++h) {    // components c=2h (b=c&3), c=2h+1
            int dd = d0 + (h >> 1);
            int bA = (2 * h) & 3, bB = (2 * h + 1) & 3;
            Alds[(bA * 7 + m) * PLN + r * 40 + dd] = (unsigned short)(vals[h] & 0xffffu);
            Alds[(bB * 7 + m) * PLN + r * 40 + dd] = (unsigned short)(vals[h] >> 16);
        }
    }
    __syncthreads();

    f32x4 acc[BATCH];
#pragma unroll
    for (int b = 0; b < BATCH; ++b)
        acc[b] = (f32x4){bo, bo, bo, bo};

#pragma unroll
    for (int m = 0; m < MSTEPS; ++m) {
#pragma unroll
        for (int b = 0; b < BATCH; ++b) {
            short8 a = *(const short8*)&Alds[(b * 7 + m) * PLN + col * 40 + quad * 8];
            acc[b] = __builtin_amdgcn_mfma_f32_16x16x32_bf16(a, bfrag[m], acc[b], 0, 0, 0);
        }
    }

    // C/D: col = lane&15 (=o), row = quad*4 + reg (=node)
#pragma unroll
    for (int b = 0; b < BATCH; ++b) {
#pragma unroll
        for (int reg = 0; reg < 4; ++reg) {
            int n = n0 + quad * 4 + reg;
            out[((size_t)b * N_NODES + n) * DOUT + o] = acc[b][reg];
        }
    }
}

extern "C" void kernel_launch(void* const* d_in, const int* in_sizes, int n_in,
                              void* d_out, int out_size, void* d_ws, size_t ws_size,
                              hipStream_t stream) {
    const float* inputs    = (const float*)d_in[0];
    const float* edge_vals = (const float*)d_in[1];
    const float* W         = (const float*)d_in[2];
    const float* bias      = (const float*)d_in[3];
    const int*   edge_src  = (const int*)d_in[4];
    const int*   edge_dst  = (const int*)d_in[5];
    float* out = (float*)d_out;
    const int E = in_sizes[1] / 2;   // edges per support

    unsigned short* xs = (unsigned short*)d_ws;              // N*896 bf16 = 35.84 MB
    int* cnt      = (int*)(xs + (size_t)N_NODES * NROW);     // 2*N
    int* row_ptr  = cnt + 2 * N_NODES;                       // 2*(N+1)
    int* cursor   = row_ptr + 2 * (N_NODES + 1);             // 2*N
    int* csr_src  = cursor + 2 * N_NODES;                    // 2*E
    float* csr_val = (float*)(csr_src + 2 * E);              // 2*E

    const int tgrid  = (N_NODES * ROW + 255) / 256;
    const int egrid  = (2 * E + 255) / 256;
    const int rgrid  = N_NODES / 4;        // 4 nodes(waves)/block, exact
    const int epgrid = N_NODES / 16;       // 1250 tiles

    // ---- CSR build for both supports ----
    zero_cnt_k<<<(2 * N_NODES + 255) / 256, 256, 0, stream>>>(cnt);
    hist_k<<<egrid, 256, 0, stream>>>(edge_dst, cnt, E);
    scan_k<<<2, 1024, 0, stream>>>(cnt, row_ptr, cursor);
    scatter_k<<<egrid, 256, 0, stream>>>(edge_src, edge_dst, edge_vals, cursor,
                                         csr_src, csr_val, E);

    const int* rp0 = row_ptr;   const int* rp1 = row_ptr + (N_NODES + 1);
    const int* cs0 = csr_src;   const int* cs1 = csr_src + E;
    const float* cv0 = csr_val; const float* cv1 = csr_val + E;

    // xs_m slice base = xs + m*128 (node stride NROW elements)
    unsigned short* X0 = xs + 0 * ROW;
    unsigned short* X1 = xs + 1 * ROW;
    unsigned short* X2 = xs + 2 * ROW;
    unsigned short* X3 = xs + 3 * ROW;
    unsigned short* X4 = xs + 4 * ROW;
    unsigned short* X5 = xs + 5 * ROW;
    unsigned short* X6 = xs + 6 * ROW;

    transpose_in_k<<<tgrid, 256, 0, stream>>>(inputs, xs);

    // support 0: xs1 = A0 x0 ; xs2 = 2 A0 xs1 - xs0 ; xs3 = 2 A0 xs2 - xs1
    spmm_row_k<<<rgrid, 256, 0, stream>>>(rp0, cs0, cv0, X0, nullptr, X1, 1.0f);
    spmm_row_k<<<rgrid, 256, 0, stream>>>(rp0, cs0, cv0, X1, X0,      X2, 2.0f);
    spmm_row_k<<<rgrid, 256, 0, stream>>>(rp0, cs0, cv0, X2, X1,      X3, 2.0f);
    // support 1 (aliasing quirk: starts from xs2)
    spmm_row_k<<<rgrid, 256, 0, stream>>>(rp1, cs1, cv1, X2, nullptr, X4, 1.0f);
    spmm_row_k<<<rgrid, 256, 0, stream>>>(rp1, cs1, cv1, X4, X2,      X5, 2.0f);
    spmm_row_k<<<rgrid, 256, 0, stream>>>(rp1, cs1, cv1, X5, X4,      X6, 2.0f);

    epilogue_mfma_k<<<epgrid, 256, 0, stream>>>(xs, W, bias, out);
}

// Round 5
// 395.951 us; speedup vs baseline: 18.6995x; 1.3447x over previous
//
#include <hip/hip_runtime.h>

// Problem constants (from reference)
#define N_NODES 20000
#define BATCH   4
#define DIN     32
#define DOUT    64
#define MSTEPS  7            // M = MAX_STEP*S + 1
#define ROW     128          // DIN*BATCH, channels per node
#define NROW    896          // ROW*MSTEPS elements per node (all m packed), bf16
#define NROWU   448          // NROW in uints
#define PLN     656          // LDS plane stride (shorts): 16 rows * 40 + 16 pad
#define NB      79           // scan blocks per support: 79*256 >= 20000

typedef short  short8 __attribute__((ext_vector_type(8)));
typedef float  f32x4  __attribute__((ext_vector_type(4)));

__device__ __forceinline__ unsigned short f2bf(float f) {
    unsigned u = __float_as_uint(f);
    unsigned r = u + 0x7fff + ((u >> 16) & 1);   // RNE to bf16
    return (unsigned short)(r >> 16);
}
__device__ __forceinline__ float bf_lo(unsigned p) { return __uint_as_float(p << 16); }
__device__ __forceinline__ float bf_hi(unsigned p) { return __uint_as_float(p & 0xffff0000u); }

// xs[n*896 + d*4 + b] = bf16(inputs[b*N*D + n*D + d])   (slice m=0)
__global__ void transpose_in_k(const float* __restrict__ in, unsigned short* __restrict__ xs) {
    int tid = blockIdx.x * 256 + threadIdx.x;
    if (tid >= N_NODES * ROW) return;
    int b = tid & 3;
    int d = (tid >> 2) & 31;
    int n = tid >> 7;
    xs[(size_t)n * NROW + d * 4 + b] = f2bf(in[(b * N_NODES + n) * DIN + d]);
}

// ---- CSR build (per call; same work every call) ----

__global__ void zero_cnt_k(int* __restrict__ cnt) {
    int i = blockIdx.x * 256 + threadIdx.x;
    if (i < 2 * N_NODES) cnt[i] = 0;
}

__global__ void hist_k(const int* __restrict__ dst, int* __restrict__ cnt, int E) {
    int i = blockIdx.x * 256 + threadIdx.x;
    if (i >= 2 * E) return;
    int s = (i >= E) ? 1 : 0;
    atomicAdd(&cnt[s * N_NODES + dst[i]], 1);
}

// phase 1: per-block inclusive scan of 256 counts; emit block sums
__global__ void scan1_k(const int* __restrict__ cnt, int* __restrict__ incl,
                        int* __restrict__ bsum) {
    __shared__ int sh[256];
    int s = (blockIdx.x >= NB) ? 1 : 0;
    int blk = blockIdx.x - s * NB;
    int t = threadIdx.x;
    int i = blk * 256 + t;
    int v = (i < N_NODES) ? cnt[s * N_NODES + i] : 0;
    sh[t] = v;
    __syncthreads();
    for (int off = 1; off < 256; off <<= 1) {
        int add = (t >= off) ? sh[t - off] : 0;
        __syncthreads();
        sh[t] += add;
        __syncthreads();
    }
    if (i < N_NODES) incl[s * N_NODES + i] = sh[t];
    if (t == 255) bsum[s * NB + blk] = sh[255];
}

// phase 2: exclusive scan of the 79 block sums per support (one block, both supports)
__global__ void scan2_k(int* __restrict__ bsum) {
    __shared__ int sh[256];
    int t = threadIdx.x;
    int s = t >> 7, j = t & 127;
    int v = (j < NB) ? bsum[s * NB + j] : 0;
    sh[t] = v;
    __syncthreads();
    for (int off = 1; off < 128; off <<= 1) {
        int add = (j >= off) ? sh[t - off] : 0;
        __syncthreads();
        sh[t] += add;
        __syncthreads();
    }
    if (j < NB) bsum[s * NB + j] = sh[t] - v;   // exclusive
}

// phase 3: row_ptr (N+1) and cursor (exclusive offsets)
__global__ void scan3_k(const int* __restrict__ incl, const int* __restrict__ bsum,
                        const int* __restrict__ cnt, int* __restrict__ row_ptr,
                        int* __restrict__ cursor) {
    int s = (blockIdx.x >= NB) ? 1 : 0;
    int blk = blockIdx.x - s * NB;
    int i = blk * 256 + threadIdx.x;
    if (i >= N_NODES) return;
    int total = incl[s * N_NODES + i] + bsum[s * NB + blk];
    row_ptr[s * (N_NODES + 1) + i + 1] = total;
    cursor[s * N_NODES + i] = total - cnt[s * N_NODES + i];
    if (i == 0) row_ptr[s * (N_NODES + 1)] = 0;
}

// interleaved CSR: one 8 B store per edge (1 dirty sector instead of 2)
__global__ void scatter_k(const int* __restrict__ src, const int* __restrict__ dst,
                          const float* __restrict__ vals, int* __restrict__ cursor,
                          int2* __restrict__ csr, int E) {
    int i = blockIdx.x * 256 + threadIdx.x;
    if (i >= 2 * E) return;
    int s = (i >= E) ? 1 : 0;
    int d = dst[i];
    int pos = atomicAdd(&cursor[s * N_NODES + d], 1);
    csr[(size_t)s * E + pos] = make_int2(src[i], __float_as_int(vals[i]));
}

// ---- SpMM gather, bf16 states, unroll-4 for MLP ----
// y_row[n] = bf16( alpha * sum val*x_row[src]  - prev_row[n] )
__global__ void spmm_row_k(const int* __restrict__ row_ptr, const int2* __restrict__ csr,
                           const unsigned short* __restrict__ x,
                           const unsigned short* __restrict__ xprev,
                           unsigned short* __restrict__ y, float alpha) {
    int node = blockIdx.x * 4 + (threadIdx.x >> 6);
    if (node >= N_NODES) return;
    int lane = threadIdx.x & 63;
    int start = row_ptr[node], end = row_ptr[node + 1];
    const unsigned* xb = (const unsigned*)x;
    float l0 = 0.f, h0 = 0.f, l1 = 0.f, h1 = 0.f;
    float l2 = 0.f, h2 = 0.f, l3 = 0.f, h3 = 0.f;
    int e = start;
    for (; e + 4 <= end; e += 4) {
        int2 c0 = csr[e], c1 = csr[e + 1], c2 = csr[e + 2], c3 = csr[e + 3];
        unsigned p0 = xb[(size_t)c0.x * NROWU + lane];
        unsigned p1 = xb[(size_t)c1.x * NROWU + lane];
        unsigned p2 = xb[(size_t)c2.x * NROWU + lane];
        unsigned p3 = xb[(size_t)c3.x * NROWU + lane];
        float v0 = __int_as_float(c0.y), v1 = __int_as_float(c1.y);
        float v2 = __int_as_float(c2.y), v3 = __int_as_float(c3.y);
        l0 = fmaf(v0, bf_lo(p0), l0);  h0 = fmaf(v0, bf_hi(p0), h0);
        l1 = fmaf(v1, bf_lo(p1), l1);  h1 = fmaf(v1, bf_hi(p1), h1);
        l2 = fmaf(v2, bf_lo(p2), l2);  h2 = fmaf(v2, bf_hi(p2), h2);
        l3 = fmaf(v3, bf_lo(p3), l3);  h3 = fmaf(v3, bf_hi(p3), h3);
    }
    for (; e < end; ++e) {
        int2 c0 = csr[e];
        unsigned p0 = xb[(size_t)c0.x * NROWU + lane];
        float v0 = __int_as_float(c0.y);
        l0 = fmaf(v0, bf_lo(p0), l0);  h0 = fmaf(v0, bf_hi(p0), h0);
    }
    float r0 = alpha * ((l0 + l1) + (l2 + l3));
    float r1 = alpha * ((h0 + h1) + (h2 + h3));
    if (xprev) {
        unsigned pp = ((const unsigned*)xprev)[(size_t)node * NROWU + lane];
        r0 -= bf_lo(pp);
        r1 -= bf_hi(pp);
    }
    unsigned po = (unsigned)f2bf(r0) | ((unsigned)f2bf(r1) << 16);
    ((unsigned*)y)[(size_t)node * NROWU + lane] = po;
}

// ---- MFMA epilogue: out[b,n,o] = bias[o] + sum_{k} A[(b,n),k] * W[o,k]
// (unchanged from R3 — verified correct)
__global__ void __launch_bounds__(256) epilogue_mfma_k(const unsigned short* __restrict__ xs,
                                                       const float* __restrict__ W,
                                                       const float* __restrict__ bias,
                                                       float* __restrict__ out) {
    __shared__ unsigned short Alds[28 * PLN];   // 36736 B
    int tid = threadIdx.x;
    int lane = tid & 63, ot = tid >> 6;
    int col = lane & 15, quad = lane >> 4;
    int o = ot * 16 + col;

    short8 bfrag[MSTEPS];
#pragma unroll
    for (int m = 0; m < MSTEPS; ++m) {
        short8 bf;
#pragma unroll
        for (int j = 0; j < 8; ++j)
            bf[j] = (short)f2bf(W[o * 224 + (quad * 8 + j) * 7 + m]);
        bfrag[m] = bf;
    }
    float bo = bias[o];

    int n0 = blockIdx.x * 16;
    const uint4* src = (const uint4*)(xs + (size_t)n0 * NROW);   // 1792 uint4
#pragma unroll
    for (int it = 0; it < 7; ++it) {
        int idx = tid + it * 256;
        uint4 q = src[idx];
        int r    = idx / 112;            // node row 0..15
        int off8 = idx - r * 112;        // element-octet within row
        int m    = off8 >> 4;
        int d0   = (off8 & 15) * 2;
        unsigned vals[4] = {q.x, q.y, q.z, q.w};
#pragma unroll
        for (int h = 0; h < 4; ++h) {
            int dd = d0 + (h >> 1);
            int bA = (2 * h) & 3, bB = (2 * h + 1) & 3;
            Alds[(bA * 7 + m) * PLN + r * 40 + dd] = (unsigned short)(vals[h] & 0xffffu);
            Alds[(bB * 7 + m) * PLN + r * 40 + dd] = (unsigned short)(vals[h] >> 16);
        }
    }
    __syncthreads();

    f32x4 acc[BATCH];
#pragma unroll
    for (int b = 0; b < BATCH; ++b)
        acc[b] = (f32x4){bo, bo, bo, bo};

#pragma unroll
    for (int m = 0; m < MSTEPS; ++m) {
#pragma unroll
        for (int b = 0; b < BATCH; ++b) {
            short8 a = *(const short8*)&Alds[(b * 7 + m) * PLN + col * 40 + quad * 8];
            acc[b] = __builtin_amdgcn_mfma_f32_16x16x32_bf16(a, bfrag[m], acc[b], 0, 0, 0);
        }
    }

#pragma unroll
    for (int b = 0; b < BATCH; ++b) {
#pragma unroll
        for (int reg = 0; reg < 4; ++reg) {
            int n = n0 + quad * 4 + reg;
            out[((size_t)b * N_NODES + n) * DOUT + o] = acc[b][reg];
        }
    }
}

extern "C" void kernel_launch(void* const* d_in, const int* in_sizes, int n_in,
                              void* d_out, int out_size, void* d_ws, size_t ws_size,
                              hipStream_t stream) {
    const float* inputs    = (const float*)d_in[0];
    const float* edge_vals = (const float*)d_in[1];
    const float* W         = (const float*)d_in[2];
    const float* bias      = (const float*)d_in[3];
    const int*   edge_src  = (const int*)d_in[4];
    const int*   edge_dst  = (const int*)d_in[5];
    float* out = (float*)d_out;
    const int E = in_sizes[1] / 2;   // edges per support

    unsigned short* xs = (unsigned short*)d_ws;              // N*896 bf16 = 35.84 MB
    int* cnt      = (int*)(xs + (size_t)N_NODES * NROW);     // 2*N
    int* row_ptr  = cnt + 2 * N_NODES;                       // 2*(N+1)
    int* cursor   = row_ptr + 2 * (N_NODES + 1);             // 2*N
    int* incl     = cursor + 2 * N_NODES;                    // 2*N
    int* bsum     = incl + 2 * N_NODES;                      // 2*NB
    int2* csr     = (int2*)(bsum + 2 * NB + 2);              // 2*E int2

    const int tgrid  = (N_NODES * ROW + 255) / 256;
    const int egrid  = (2 * E + 255) / 256;
    const int rgrid  = N_NODES / 4;        // 4 nodes(waves)/block, exact
    const int epgrid = N_NODES / 16;       // 1250 tiles

    // ---- CSR build for both supports ----
    zero_cnt_k<<<(2 * N_NODES + 255) / 256, 256, 0, stream>>>(cnt);
    hist_k<<<egrid, 256, 0, stream>>>(edge_dst, cnt, E);
    scan1_k<<<2 * NB, 256, 0, stream>>>(cnt, incl, bsum);
    scan2_k<<<1, 256, 0, stream>>>(bsum);
    scan3_k<<<2 * NB, 256, 0, stream>>>(incl, bsum, cnt, row_ptr, cursor);
    scatter_k<<<egrid, 256, 0, stream>>>(edge_src, edge_dst, edge_vals, cursor, csr, E);

    const int* rp0 = row_ptr;   const int* rp1 = row_ptr + (N_NODES + 1);
    const int2* cs0 = csr;      const int2* cs1 = csr + E;

    // xs_m slice base = xs + m*128 (node stride NROW elements)
    unsigned short* X0 = xs + 0 * ROW;
    unsigned short* X1 = xs + 1 * ROW;
    unsigned short* X2 = xs + 2 * ROW;
    unsigned short* X3 = xs + 3 * ROW;
    unsigned short* X4 = xs + 4 * ROW;
    unsigned short* X5 = xs + 5 * ROW;
    unsigned short* X6 = xs + 6 * ROW;

    transpose_in_k<<<tgrid, 256, 0, stream>>>(inputs, xs);

    // support 0: xs1 = A0 x0 ; xs2 = 2 A0 xs1 - xs0 ; xs3 = 2 A0 xs2 - xs1
    spmm_row_k<<<rgrid, 256, 0, stream>>>(rp0, cs0, X0, nullptr, X1, 1.0f);
    spmm_row_k<<<rgrid, 256, 0, stream>>>(rp0, cs0, X1, X0,      X2, 2.0f);
    spmm_row_k<<<rgrid, 256, 0, stream>>>(rp0, cs0, X2, X1,      X3, 2.0f);
    // support 1 (aliasing quirk: starts from xs2)
    spmm_row_k<<<rgrid, 256, 0, stream>>>(rp1, cs1, X2, nullptr, X4, 1.0f);
    spmm_row_k<<<rgrid, 256, 0, stream>>>(rp1, cs1, X4, X2,      X5, 2.0f);
    spmm_row_k<<<rgrid, 256, 0, stream>>>(rp1, cs1, X5, X4,      X6, 2.0f);

    epilogue_mfma_k<<<epgrid, 256, 0, stream>>>(xs, W, bias, out);
}